// Round 4
// baseline (296.676 us; speedup 1.0000x reference)
//
#include <hip/hip_runtime.h>
#include <hip/hip_bf16.h>

// Problem constants
#define B_  8
#define CIN 32
#define COUT 16
#define OGRP 8          // output channels per block (COUT split in 2)
#define K_  4
#define HID 9
#define HIN 256
#define WIN 256
#define HOUT 512
#define WOUT 512
#define TEMP 34.0f
#define EPS_ 1e-5f

typedef float float4u __attribute__((ext_vector_type(4), aligned(4)));

// ---------------------------------------------------------------------------
// Kernel A: pooled[b][c] = mean over HxW of x[b][c]  (== mean of upsampled)
// ---------------------------------------------------------------------------
__global__ __launch_bounds__(256) void pool_kernel(const float* __restrict__ x,
                                                   float* __restrict__ pooled) {
    int bc = blockIdx.x;  // 0..255  (b*32+c)
    const float4* p = (const float4*)(x + (size_t)bc * (HIN * WIN));
    float s = 0.f;
    for (int i = threadIdx.x; i < (HIN * WIN) / 4; i += 256) {
        float4 v = p[i];
        s += v.x + v.y + v.z + v.w;
    }
    #pragma unroll
    for (int off = 32; off > 0; off >>= 1) s += __shfl_down(s, off);
    __shared__ float red[4];
    if ((threadIdx.x & 63) == 0) red[threadIdx.x >> 6] = s;
    __syncthreads();
    if (threadIdx.x == 0)
        pooled[bc] = (red[0] + red[1] + red[2] + red[3]) * (1.f / (HIN * WIN));
}

// ---------------------------------------------------------------------------
// Kernel B: attention -> aggregated, BN-folded, parity-combined 2x2 weights
// ---------------------------------------------------------------------------
__global__ __launch_bounds__(256) void attn_weights_kernel(
    const float* __restrict__ pooled, const float* __restrict__ weight,
    const float* __restrict__ bias, const float* __restrict__ fc1_w,
    const float* __restrict__ fc2_w, const float* __restrict__ fc2_b,
    const float* __restrict__ gamma, const float* __restrict__ beta,
    const float* __restrict__ mean, const float* __restrict__ var,
    float* __restrict__ wc, float* __restrict__ bias_eff) {
    int b = blockIdx.x;
    __shared__ float attn[K_];
    if (threadIdx.x == 0) {
        const float* pb = pooled + b * CIN;
        float h[HID];
        for (int j = 0; j < HID; ++j) {
            float s = 0.f;
            for (int c = 0; c < CIN; ++c) s += pb[c] * fc1_w[j * CIN + c];
            h[j] = fmaxf(s, 0.f);
        }
        float lg[K_];
        float mx = -1e30f;
        for (int k = 0; k < K_; ++k) {
            float s = fc2_b[k];
            for (int j = 0; j < HID; ++j) s += h[j] * fc2_w[k * HID + j];
            lg[k] = s * (1.f / TEMP);
            mx = fmaxf(mx, lg[k]);
        }
        float den = 0.f;
        for (int k = 0; k < K_; ++k) { lg[k] = expf(lg[k] - mx); den += lg[k]; }
        for (int k = 0; k < K_; ++k) attn[k] = lg[k] / den;
    }
    __syncthreads();
    float a0 = attn[0], a1 = attn[1], a2 = attn[2], a3v = attn[3];

    for (int p = threadIdx.x; p < COUT * CIN; p += 256) {
        int o = p >> 5, i = p & 31;
        float scale = gamma[o] / sqrtf(var[o] + EPS_);
        const float* w0 = weight + ((size_t)(0 * COUT + o) * CIN + i) * 9;
        const int kstr = COUT * CIN * 9;  // 4608
        float a3w[9];
        #pragma unroll
        for (int t = 0; t < 9; ++t)
            a3w[t] = scale * (a0 * w0[t] + a1 * w0[kstr + t] +
                              a2 * w0[2 * kstr + t] + a3v * w0[3 * kstr + t]);
        float tmp[2][2][3];
        #pragma unroll
        for (int kx = 0; kx < 3; ++kx) {
            tmp[0][0][kx] = a3w[0 * 3 + kx];
            tmp[0][1][kx] = a3w[1 * 3 + kx] + a3w[2 * 3 + kx];
            tmp[1][0][kx] = a3w[0 * 3 + kx] + a3w[1 * 3 + kx];
            tmp[1][1][kx] = a3w[2 * 3 + kx];
        }
        float* dst = wc + ((size_t)(b * COUT + o) * CIN + i) * 16;
        #pragma unroll
        for (int py = 0; py < 2; ++py)
            #pragma unroll
            for (int px = 0; px < 2; ++px)
                #pragma unroll
                for (int u = 0; u < 2; ++u)
                    #pragma unroll
                    for (int v = 0; v < 2; ++v) {
                        const float* t = tmp[py][u];
                        float val = (px == 0) ? (v == 0 ? t[0] : t[1] + t[2])
                                              : (v == 0 ? t[0] + t[1] : t[2]);
                        dst[((py * 2 + px) * 2 + u) * 2 + v] = val;
                    }
    }
    if (threadIdx.x < COUT) {
        int o = threadIdx.x;
        float scale = gamma[o] / sqrtf(var[o] + EPS_);
        float shift = beta[o] - mean[o] * scale;
        float s = a0 * bias[0 * COUT + o] + a1 * bias[1 * COUT + o] +
                  a2 * bias[2 * COUT + o] + a3v * bias[3 * COUT + o];
        bias_eff[b * COUT + o] = s * scale + shift;
    }
}

// ---------------------------------------------------------------------------
// Kernel C: fused upsample+conv+BN+ReLU via parity decomposition.
// Block: (b, 8-o group, 32x32 input-base tile == 64x64 output tile).
// Thread (ty,tx): 2x2 bases x 8 o  -> acc[8][2][2][2][2] = 128 VGPRs.
// Weights: staged to LDS once (16 KiB), read as uniform-address
// ds_read_b128 (broadcast). Input: 4 unaligned dwordx4 per channel from
// global (L1/L2-hot), double-buffered across the i-loop.
// Per channel per thread: 512 FMA : 32 ds_read : 4 vmem.
// ---------------------------------------------------------------------------
__global__ __launch_bounds__(256, 2) void conv_kernel(
    const float* __restrict__ x, const float* __restrict__ wc,
    const float* __restrict__ bias_eff, float* __restrict__ out) {
    const int tile = blockIdx.x;            // 0..63
    const int o0 = blockIdx.y * OGRP;       // 0 or 8
    const int b = blockIdx.z;               // 0..7
    const int tile_y = tile >> 3, tile_x = tile & 7;
    const int r0 = tile_y * 32, c0 = tile_x * 32;
    const int tid = threadIdx.x;
    const int ty = tid >> 4, tx = tid & 15;
    const int row0 = r0 + 2 * ty;   // this thread's first base row
    const int col0 = c0 + 2 * tx;   // this thread's first base col

    __shared__ float wlds[CIN * OGRP * 16];  // [i][o][16] = 16 KiB

    // stage this block's weights once: thread -> (i = tid>>3, o = tid&7)
    {
        int i = tid >> 3, o = tid & 7;
        const float* src = wc + (((size_t)(b * COUT + o0 + o) * CIN + i) << 4);
        float* dst = wlds + (((i << 3) + o) << 4);
        #pragma unroll
        for (int q = 0; q < 4; ++q)
            ((float4*)dst)[q] = ((const float4*)src)[q];
    }
    __syncthreads();

    float acc[OGRP][2][2][2][2] = {};  // [o][br][bc][py][px]
    const float* xb = x + (size_t)b * CIN * (HIN * WIN);

    // 512 FMAs for one channel given the thread's 4x4 input patch
    auto compute = [&](int i, const float (&in)[4][4]) {
        const float* wrow = &wlds[i << 7];  // i*8*16
        #pragma unroll
        for (int o = 0; o < OGRP; ++o) {
            float w[16];
            #pragma unroll
            for (int q = 0; q < 4; ++q)
                ((float4*)w)[q] = ((const float4*)(wrow + (o << 4)))[q];
            #pragma unroll
            for (int br = 0; br < 2; ++br)
                #pragma unroll
                for (int bc = 0; bc < 2; ++bc)
                    #pragma unroll
                    for (int py = 0; py < 2; ++py)
                        #pragma unroll
                        for (int px = 0; px < 2; ++px) {
                            float s = acc[o][br][bc][py][px];
                            #pragma unroll
                            for (int u = 0; u < 2; ++u)
                                #pragma unroll
                                for (int v = 0; v < 2; ++v)
                                    s = fmaf(w[((py * 2 + px) * 2 + u) * 2 + v],
                                             in[br + py + u][bc + px + v], s);
                            acc[o][br][bc][py][px] = s;
                        }
        }
    };

    // double-buffered i-loop shared by both load paths
    auto run = [&](auto&& loadPatch) {
        float A[4][4], Bv[4][4];
        loadPatch(0, A);
        for (int i = 0; i < CIN; i += 2) {
            loadPatch(i + 1, Bv);
            compute(i, A);
            if (i + 2 < CIN) loadPatch(i + 2, A);
            compute(i + 1, Bv);
        }
    };

    const bool interior = (tile_y > 0) & (tile_y < 7) & (tile_x > 0) &
                          (tile_x < 7);
    if (interior) {
        const float* p0 = xb + (size_t)(row0 - 1) * WIN + (col0 - 1);
        auto loadFast = [&](int i, float (&buf)[4][4]) {
            const float* p = p0 + (size_t)i * (HIN * WIN);
            #pragma unroll
            for (int u = 0; u < 4; ++u) {
                float4u t = *(const float4u*)(p + u * WIN);
                buf[u][0] = t.x; buf[u][1] = t.y;
                buf[u][2] = t.z; buf[u][3] = t.w;
            }
        };
        run(loadFast);
    } else {
        int roff[4], coff[4];
        float mr[4], mc[4];
        #pragma unroll
        for (int u = 0; u < 4; ++u) {
            int gr = row0 - 1 + u;
            mr[u] = ((unsigned)gr < (unsigned)HIN) ? 1.f : 0.f;
            roff[u] = min(max(gr, 0), HIN - 1) * WIN;
            int gc = col0 - 1 + u;
            mc[u] = ((unsigned)gc < (unsigned)WIN) ? 1.f : 0.f;
            coff[u] = min(max(gc, 0), WIN - 1);
        }
        auto loadEdge = [&](int i, float (&buf)[4][4]) {
            const float* p = xb + (size_t)i * (HIN * WIN);
            #pragma unroll
            for (int u = 0; u < 4; ++u)
                #pragma unroll
                for (int v = 0; v < 4; ++v)
                    buf[u][v] = mr[u] * mc[v] * p[roff[u] + coff[v]];
        };
        run(loadEdge);
    }

    // Epilogue: bias + ReLU, float4 stores (16B-aligned, coalesced per wave)
    #pragma unroll
    for (int o = 0; o < OGRP; ++o) {
        const float bse = bias_eff[b * COUT + o0 + o];
        float* ob = out + (size_t)(b * COUT + o0 + o) * (HOUT * WOUT);
        #pragma unroll
        for (int br = 0; br < 2; ++br)
            #pragma unroll
            for (int py = 0; py < 2; ++py) {
                int y = 2 * (row0 + br) + py;
                float4 vst;
                vst.x = fmaxf(acc[o][br][0][py][0] + bse, 0.f);
                vst.y = fmaxf(acc[o][br][0][py][1] + bse, 0.f);
                vst.z = fmaxf(acc[o][br][1][py][0] + bse, 0.f);
                vst.w = fmaxf(acc[o][br][1][py][1] + bse, 0.f);
                *(float4*)&ob[(size_t)y * WOUT + 2 * col0] = vst;
            }
    }
}

extern "C" void kernel_launch(void* const* d_in, const int* in_sizes, int n_in,
                              void* d_out, int out_size, void* d_ws, size_t ws_size,
                              hipStream_t stream) {
    const float* x      = (const float*)d_in[0];
    const float* weight = (const float*)d_in[1];
    const float* bias   = (const float*)d_in[2];
    const float* fc1_w  = (const float*)d_in[3];
    const float* fc2_w  = (const float*)d_in[4];
    const float* fc2_b  = (const float*)d_in[5];
    const float* bn_g   = (const float*)d_in[6];
    const float* bn_b   = (const float*)d_in[7];
    const float* bn_m   = (const float*)d_in[8];
    const float* bn_v   = (const float*)d_in[9];
    float* out = (float*)d_out;

    float* ws = (float*)d_ws;
    float* pooled   = ws;            // 256 floats
    float* bias_eff = ws + 256;      // 128 floats
    float* wcbuf    = ws + 512;      // 8*16*32*16 = 65536 floats

    pool_kernel<<<dim3(B_ * CIN), dim3(256), 0, stream>>>(x, pooled);
    attn_weights_kernel<<<dim3(B_), dim3(256), 0, stream>>>(
        pooled, weight, bias, fc1_w, fc2_w, fc2_b, bn_g, bn_b, bn_m, bn_v,
        wcbuf, bias_eff);
    conv_kernel<<<dim3(64, COUT / OGRP, B_), dim3(256), 0, stream>>>(
        x, wcbuf, bias_eff, out);
}

// Round 5
// 188.614 us; speedup vs baseline: 1.5729x; 1.5729x over previous
//
#include <hip/hip_runtime.h>
#include <hip/hip_bf16.h>

// Problem constants
#define B_  8
#define CIN 32
#define COUT 16
#define OGRP 8          // output channels per block (COUT split in 2)
#define K_  4
#define HID 9
#define HIN 256
#define WIN 256
#define HOUT 512
#define WOUT 512
#define TEMP 34.0f
#define EPS_ 1e-5f

typedef float float4u __attribute__((ext_vector_type(4), aligned(4)));

// ---------------------------------------------------------------------------
// Kernel A: pooled[b][c] = mean over HxW of x[b][c]  (== mean of upsampled)
// ---------------------------------------------------------------------------
__global__ __launch_bounds__(256) void pool_kernel(const float* __restrict__ x,
                                                   float* __restrict__ pooled) {
    int bc = blockIdx.x;  // 0..255  (b*32+c)
    const float4* p = (const float4*)(x + (size_t)bc * (HIN * WIN));
    float s = 0.f;
    for (int i = threadIdx.x; i < (HIN * WIN) / 4; i += 256) {
        float4 v = p[i];
        s += v.x + v.y + v.z + v.w;
    }
    #pragma unroll
    for (int off = 32; off > 0; off >>= 1) s += __shfl_down(s, off);
    __shared__ float red[4];
    if ((threadIdx.x & 63) == 0) red[threadIdx.x >> 6] = s;
    __syncthreads();
    if (threadIdx.x == 0)
        pooled[bc] = (red[0] + red[1] + red[2] + red[3]) * (1.f / (HIN * WIN));
}

// ---------------------------------------------------------------------------
// Kernel B: attention -> aggregated, BN-folded, parity-combined 2x2 weights
// ---------------------------------------------------------------------------
__global__ __launch_bounds__(256) void attn_weights_kernel(
    const float* __restrict__ pooled, const float* __restrict__ weight,
    const float* __restrict__ bias, const float* __restrict__ fc1_w,
    const float* __restrict__ fc2_w, const float* __restrict__ fc2_b,
    const float* __restrict__ gamma, const float* __restrict__ beta,
    const float* __restrict__ mean, const float* __restrict__ var,
    float* __restrict__ wc, float* __restrict__ bias_eff) {
    int b = blockIdx.x;
    __shared__ float attn[K_];
    if (threadIdx.x == 0) {
        const float* pb = pooled + b * CIN;
        float h[HID];
        for (int j = 0; j < HID; ++j) {
            float s = 0.f;
            for (int c = 0; c < CIN; ++c) s += pb[c] * fc1_w[j * CIN + c];
            h[j] = fmaxf(s, 0.f);
        }
        float lg[K_];
        float mx = -1e30f;
        for (int k = 0; k < K_; ++k) {
            float s = fc2_b[k];
            for (int j = 0; j < HID; ++j) s += h[j] * fc2_w[k * HID + j];
            lg[k] = s * (1.f / TEMP);
            mx = fmaxf(mx, lg[k]);
        }
        float den = 0.f;
        for (int k = 0; k < K_; ++k) { lg[k] = expf(lg[k] - mx); den += lg[k]; }
        for (int k = 0; k < K_; ++k) attn[k] = lg[k] / den;
    }
    __syncthreads();
    float a0 = attn[0], a1 = attn[1], a2 = attn[2], a3v = attn[3];

    for (int p = threadIdx.x; p < COUT * CIN; p += 256) {
        int o = p >> 5, i = p & 31;
        float scale = gamma[o] / sqrtf(var[o] + EPS_);
        const float* w0 = weight + ((size_t)(0 * COUT + o) * CIN + i) * 9;
        const int kstr = COUT * CIN * 9;  // 4608
        float a3w[9];
        #pragma unroll
        for (int t = 0; t < 9; ++t)
            a3w[t] = scale * (a0 * w0[t] + a1 * w0[kstr + t] +
                              a2 * w0[2 * kstr + t] + a3v * w0[3 * kstr + t]);
        float tmp[2][2][3];
        #pragma unroll
        for (int kx = 0; kx < 3; ++kx) {
            tmp[0][0][kx] = a3w[0 * 3 + kx];
            tmp[0][1][kx] = a3w[1 * 3 + kx] + a3w[2 * 3 + kx];
            tmp[1][0][kx] = a3w[0 * 3 + kx] + a3w[1 * 3 + kx];
            tmp[1][1][kx] = a3w[2 * 3 + kx];
        }
        float* dst = wc + ((size_t)(b * COUT + o) * CIN + i) * 16;
        #pragma unroll
        for (int py = 0; py < 2; ++py)
            #pragma unroll
            for (int px = 0; px < 2; ++px)
                #pragma unroll
                for (int u = 0; u < 2; ++u)
                    #pragma unroll
                    for (int v = 0; v < 2; ++v) {
                        const float* t = tmp[py][u];
                        float val = (px == 0) ? (v == 0 ? t[0] : t[1] + t[2])
                                              : (v == 0 ? t[0] + t[1] : t[2]);
                        dst[((py * 2 + px) * 2 + u) * 2 + v] = val;
                    }
    }
    if (threadIdx.x < COUT) {
        int o = threadIdx.x;
        float scale = gamma[o] / sqrtf(var[o] + EPS_);
        float shift = beta[o] - mean[o] * scale;
        float s = a0 * bias[0 * COUT + o] + a1 * bias[1 * COUT + o] +
                  a2 * bias[2 * COUT + o] + a3v * bias[3 * COUT + o];
        bias_eff[b * COUT + o] = s * scale + shift;
    }
}

// ---------------------------------------------------------------------------
// Kernel C: fused upsample+conv+BN+ReLU via parity decomposition.
// Block: (b, 8-o group, 16x32 input-base tile == 32x64 output tile).
// Thread (ty,tx): 1x2 bases x 8 o -> acc[8][2][2][2] = 64 VGPRs (no spill,
// <=128 total -> 4 waves/SIMD). Weights staged to LDS once (16 KiB), read
// as uniform-address ds_read_b128 broadcasts. Input: 3 unaligned dwordx4
// per channel direct from global (L2-hot), latency hidden by TLP.
// Per channel per thread: 256 FMA : 32 ds_read(broadcast) : 3 vmem.
// ---------------------------------------------------------------------------
__global__ __launch_bounds__(256) void conv_kernel(
    const float* __restrict__ x, const float* __restrict__ wc,
    const float* __restrict__ bias_eff, float* __restrict__ out) {
    const int tile = blockIdx.x;            // 0..127
    const int o0 = blockIdx.y * OGRP;       // 0 or 8
    const int b = blockIdx.z;               // 0..7
    const int tile_y = tile >> 3, tile_x = tile & 7;   // 16 x 8 tiles
    const int r0 = tile_y * 16, c0 = tile_x * 32;
    const int tid = threadIdx.x;
    const int ty = tid >> 4, tx = tid & 15;
    const int row = r0 + ty;          // this thread's base row
    const int col0 = c0 + 2 * tx;     // this thread's first base col

    __shared__ float wlds[CIN * OGRP * 16];  // [i][o][16] = 16 KiB

    // stage this block's weights once: thread -> (i = tid>>3, o = tid&7)
    {
        int i = tid >> 3, o = tid & 7;
        const float* src = wc + (((size_t)(b * COUT + o0 + o) * CIN + i) << 4);
        float* dst = wlds + (((i << 3) + o) << 4);
        #pragma unroll
        for (int q = 0; q < 4; ++q)
            ((float4*)dst)[q] = ((const float4*)src)[q];
    }
    __syncthreads();

    float acc[OGRP][2][2][2] = {};  // [o][bc][py][px]
    const float* xb = x + (size_t)b * CIN * (HIN * WIN);

    // 256 FMAs for one channel given the thread's 3x4 input patch
    auto compute = [&](int i, const float (&in)[3][4]) {
        const float* wrow = &wlds[i << 7];  // i*8*16
        #pragma unroll
        for (int o = 0; o < OGRP; ++o) {
            float w[16];
            #pragma unroll
            for (int q = 0; q < 4; ++q)
                ((float4*)w)[q] = ((const float4*)(wrow + (o << 4)))[q];
            #pragma unroll
            for (int bc = 0; bc < 2; ++bc)
                #pragma unroll
                for (int py = 0; py < 2; ++py)
                    #pragma unroll
                    for (int px = 0; px < 2; ++px) {
                        float s = acc[o][bc][py][px];
                        #pragma unroll
                        for (int u = 0; u < 2; ++u)
                            #pragma unroll
                            for (int v = 0; v < 2; ++v)
                                s = fmaf(w[((py * 2 + px) * 2 + u) * 2 + v],
                                         in[py + u][bc + px + v], s);
                        acc[o][bc][py][px] = s;
                    }
        }
    };

    const bool interior = (tile_y > 0) & (tile_y < 15) & (tile_x > 0) &
                          (tile_x < 7);
    if (interior) {
        const float* p0 = xb + (size_t)(row - 1) * WIN + (col0 - 1);
        #pragma unroll 2
        for (int i = 0; i < CIN; ++i) {
            const float* p = p0 + (size_t)i * (HIN * WIN);
            float in[3][4];
            #pragma unroll
            for (int u = 0; u < 3; ++u) {
                float4u t = *(const float4u*)(p + u * WIN);
                in[u][0] = t.x; in[u][1] = t.y;
                in[u][2] = t.z; in[u][3] = t.w;
            }
            compute(i, in);
        }
    } else {
        int roff[3], coff[4];
        float mr[3], mc[4];
        #pragma unroll
        for (int u = 0; u < 3; ++u) {
            int gr = row - 1 + u;
            mr[u] = ((unsigned)gr < (unsigned)HIN) ? 1.f : 0.f;
            roff[u] = min(max(gr, 0), HIN - 1) * WIN;
        }
        #pragma unroll
        for (int v = 0; v < 4; ++v) {
            int gc = col0 - 1 + v;
            mc[v] = ((unsigned)gc < (unsigned)WIN) ? 1.f : 0.f;
            coff[v] = min(max(gc, 0), WIN - 1);
        }
        #pragma unroll 2
        for (int i = 0; i < CIN; ++i) {
            const float* p = xb + (size_t)i * (HIN * WIN);
            float in[3][4];
            #pragma unroll
            for (int u = 0; u < 3; ++u)
                #pragma unroll
                for (int v = 0; v < 4; ++v)
                    in[u][v] = mr[u] * mc[v] * p[roff[u] + coff[v]];
            compute(i, in);
        }
    }

    // Epilogue: bias + ReLU, float4 stores (16B-aligned, coalesced per wave)
    #pragma unroll
    for (int o = 0; o < OGRP; ++o) {
        const float bse = bias_eff[b * COUT + o0 + o];
        float* ob = out + (size_t)(b * COUT + o0 + o) * (HOUT * WOUT);
        #pragma unroll
        for (int py = 0; py < 2; ++py) {
            int y = 2 * row + py;
            float4 vst;
            vst.x = fmaxf(acc[o][0][py][0] + bse, 0.f);
            vst.y = fmaxf(acc[o][0][py][1] + bse, 0.f);
            vst.z = fmaxf(acc[o][1][py][0] + bse, 0.f);
            vst.w = fmaxf(acc[o][1][py][1] + bse, 0.f);
            *(float4*)&ob[(size_t)y * WOUT + 2 * col0] = vst;
        }
    }
}

extern "C" void kernel_launch(void* const* d_in, const int* in_sizes, int n_in,
                              void* d_out, int out_size, void* d_ws, size_t ws_size,
                              hipStream_t stream) {
    const float* x      = (const float*)d_in[0];
    const float* weight = (const float*)d_in[1];
    const float* bias   = (const float*)d_in[2];
    const float* fc1_w  = (const float*)d_in[3];
    const float* fc2_w  = (const float*)d_in[4];
    const float* fc2_b  = (const float*)d_in[5];
    const float* bn_g   = (const float*)d_in[6];
    const float* bn_b   = (const float*)d_in[7];
    const float* bn_m   = (const float*)d_in[8];
    const float* bn_v   = (const float*)d_in[9];
    float* out = (float*)d_out;

    float* ws = (float*)d_ws;
    float* pooled   = ws;            // 256 floats
    float* bias_eff = ws + 256;      // 128 floats
    float* wcbuf    = ws + 512;      // 8*16*32*16 = 65536 floats

    pool_kernel<<<dim3(B_ * CIN), dim3(256), 0, stream>>>(x, pooled);
    attn_weights_kernel<<<dim3(B_), dim3(256), 0, stream>>>(
        pooled, weight, bias, fc1_w, fc2_w, fc2_b, bn_g, bn_b, bn_m, bn_v,
        wcbuf, bias_eff);
    conv_kernel<<<dim3(128, COUT / OGRP, B_), dim3(256), 0, stream>>>(
        x, wcbuf, bias_eff, out);
}

// Round 7
// 159.565 us; speedup vs baseline: 1.8593x; 1.1820x over previous
//
#include <hip/hip_runtime.h>
#include <hip/hip_bf16.h>

// Problem constants
#define B_  8
#define CIN 32
#define COUT 16
#define K_  4
#define HID 9
#define HIN 256
#define WIN 256
#define HW  (HIN * WIN)
#define HOUT 512
#define WOUT 512
#define TEMP 34.0f
#define EPS_ 1e-5f

typedef float float4u __attribute__((ext_vector_type(4), aligned(4)));
typedef _Float16 half2v __attribute__((ext_vector_type(2)));
typedef __fp16 fp16x2 __attribute__((ext_vector_type(2)));

__device__ inline half2v pk_f16(float a, float b) {
#if __has_builtin(__builtin_amdgcn_cvt_pkrtz)
    union { fp16x2 f; half2v h; } x;
    x.f = __builtin_amdgcn_cvt_pkrtz(a, b);
    return x.h;
#else
    half2v r; r.x = (_Float16)a; r.y = (_Float16)b; return r;
#endif
}

__device__ inline float fdot2f(half2v a, half2v b, float c) {
#if __has_builtin(__builtin_amdgcn_fdot2)
    return __builtin_amdgcn_fdot2(a, b, c, false);
#else
    return (float)a.x * (float)b.x + ((float)a.y * (float)b.y + c);
#endif
}

__device__ inline half2v u2h(unsigned u) {
    union { unsigned u; half2v h; } x; x.u = u; return x.h;
}
__device__ inline unsigned h2u(half2v h) {
    union { unsigned u; half2v h; } x; x.h = h; return x.u;
}

// ---------------------------------------------------------------------------
// Kernel A: pooled[b][c] = mean over HxW of x[b][c]  (== mean of upsampled)
// ---------------------------------------------------------------------------
__global__ __launch_bounds__(256) void pool_kernel(const float* __restrict__ x,
                                                   float* __restrict__ pooled) {
    int bc = blockIdx.x;  // 0..255  (b*32+c)
    const float4* p = (const float4*)(x + (size_t)bc * HW);
    float s = 0.f;
    for (int i = threadIdx.x; i < HW / 4; i += 256) {
        float4 v = p[i];
        s += v.x + v.y + v.z + v.w;
    }
    #pragma unroll
    for (int off = 32; off > 0; off >>= 1) s += __shfl_down(s, off);
    __shared__ float red[4];
    if ((threadIdx.x & 63) == 0) red[threadIdx.x >> 6] = s;
    __syncthreads();
    if (threadIdx.x == 0)
        pooled[bc] = (red[0] + red[1] + red[2] + red[3]) * (1.f / HW);
}

// ---------------------------------------------------------------------------
// Kernel B: attention -> aggregated, BN-folded, parity-combined 2x2 weights.
// Writes fp32 wc (for fix kernel) AND f16-packed wch (for main conv).
// wch layout: dword[((b*8+og)*32 + i)*16 + oo*8 + q], o = og*2+oo,
//             q = (py*2+px)*2+u, dword = pack(w[v=0], w[v=1]).
// ---------------------------------------------------------------------------
__global__ __launch_bounds__(256) void attn_weights_kernel(
    const float* __restrict__ pooled, const float* __restrict__ weight,
    const float* __restrict__ bias, const float* __restrict__ fc1_w,
    const float* __restrict__ fc2_w, const float* __restrict__ fc2_b,
    const float* __restrict__ gamma, const float* __restrict__ beta,
    const float* __restrict__ mean, const float* __restrict__ var,
    float* __restrict__ wc, unsigned* __restrict__ wch,
    float* __restrict__ bias_eff) {
    int b = blockIdx.x;
    __shared__ float attn[K_];
    if (threadIdx.x == 0) {
        const float* pb = pooled + b * CIN;
        float h[HID];
        for (int j = 0; j < HID; ++j) {
            float s = 0.f;
            for (int c = 0; c < CIN; ++c) s += pb[c] * fc1_w[j * CIN + c];
            h[j] = fmaxf(s, 0.f);
        }
        float lg[K_];
        float mx = -1e30f;
        for (int k = 0; k < K_; ++k) {
            float s = fc2_b[k];
            for (int j = 0; j < HID; ++j) s += h[j] * fc2_w[k * HID + j];
            lg[k] = s * (1.f / TEMP);
            mx = fmaxf(mx, lg[k]);
        }
        float den = 0.f;
        for (int k = 0; k < K_; ++k) { lg[k] = expf(lg[k] - mx); den += lg[k]; }
        for (int k = 0; k < K_; ++k) attn[k] = lg[k] / den;
    }
    __syncthreads();
    float a0 = attn[0], a1 = attn[1], a2 = attn[2], a3v = attn[3];

    for (int p = threadIdx.x; p < COUT * CIN; p += 256) {
        int o = p >> 5, i = p & 31;
        float scale = gamma[o] / sqrtf(var[o] + EPS_);
        const float* w0 = weight + ((size_t)(0 * COUT + o) * CIN + i) * 9;
        const int kstr = COUT * CIN * 9;  // 4608
        float a3w[9];
        #pragma unroll
        for (int t = 0; t < 9; ++t)
            a3w[t] = scale * (a0 * w0[t] + a1 * w0[kstr + t] +
                              a2 * w0[2 * kstr + t] + a3v * w0[3 * kstr + t]);
        float tmp[2][2][3];
        #pragma unroll
        for (int kx = 0; kx < 3; ++kx) {
            tmp[0][0][kx] = a3w[0 * 3 + kx];
            tmp[0][1][kx] = a3w[1 * 3 + kx] + a3w[2 * 3 + kx];
            tmp[1][0][kx] = a3w[0 * 3 + kx] + a3w[1 * 3 + kx];
            tmp[1][1][kx] = a3w[2 * 3 + kx];
        }
        float w16[16];
        #pragma unroll
        for (int py = 0; py < 2; ++py)
            #pragma unroll
            for (int px = 0; px < 2; ++px)
                #pragma unroll
                for (int u = 0; u < 2; ++u)
                    #pragma unroll
                    for (int v = 0; v < 2; ++v) {
                        const float* t = tmp[py][u];
                        float val = (px == 0) ? (v == 0 ? t[0] : t[1] + t[2])
                                              : (v == 0 ? t[0] + t[1] : t[2]);
                        w16[((py * 2 + px) * 2 + u) * 2 + v] = val;
                    }
        float* dst = wc + ((size_t)(b * COUT + o) * CIN + i) * 16;
        #pragma unroll
        for (int t = 0; t < 16; ++t) dst[t] = w16[t];
        unsigned* wp = wch + ((size_t)(b * 8 + (o >> 1)) * 32 + i) * 16 +
                       (o & 1) * 8;
        #pragma unroll
        for (int q = 0; q < 8; ++q)
            wp[q] = h2u(pk_f16(w16[2 * q], w16[2 * q + 1]));
    }
    if (threadIdx.x < COUT) {
        int o = threadIdx.x;
        float scale = gamma[o] / sqrtf(var[o] + EPS_);
        float shift = beta[o] - mean[o] * scale;
        float s = a0 * bias[0 * COUT + o] + a1 * bias[1 * COUT + o] +
                  a2 * bias[2 * COUT + o] + a3v * bias[3 * COUT + o];
        bias_eff[b * COUT + o] = s * scale + shift;
    }
}

// ---------------------------------------------------------------------------
// Kernel C: fused upsample+conv+BN+ReLU, f16 dot2 path.
// Block: (b, o-pair og, 64x32 input-base tile). Thread (ty,tx): 4 base rows x
// 2 base cols x 2 o -> acc[2][4][2][2][2] = 64 VGPRs.
// Per channel per thread: 6 dwordx4 loads + 18 cvt_pk + 4 broadcast
// ds_read_b128 + 128 v_dot2_f32_f16. Borders handled by CLAMPED loads
// (branch-free); contaminated outputs (y in {0,511}, x in {0..3,508..511})
// are recomputed exactly by fix_kernel afterwards.
// ---------------------------------------------------------------------------
__global__ __launch_bounds__(256) void conv_kernel(
    const float* __restrict__ x, const unsigned* __restrict__ wch,
    const float* __restrict__ bias_eff, float* __restrict__ out) {
    const int bx = blockIdx.x;          // 0..31
    const int og = blockIdx.y;          // 0..7
    const int b  = blockIdx.z;          // 0..7
    const int tile_y = bx >> 3, tile_x = bx & 7;
    const int r0 = tile_y * 64, c0 = tile_x * 32;
    const int tid = threadIdx.x;
    const int ty = tid >> 4, tx = tid & 15;
    const int row0 = r0 + 4 * ty;
    const int col0 = c0 + 2 * tx;

    __shared__ unsigned wlds[512];  // [i][oo][8] packed f16 pairs, 2 KiB
    if (tid < 128)
        ((uint4*)wlds)[tid] =
            ((const uint4*)(wch + (size_t)(b * 8 + og) * 512))[tid];
    __syncthreads();

    int roff[6];
    #pragma unroll
    for (int u = 0; u < 6; ++u)
        roff[u] = min(max(row0 - 1 + u, 0), HIN - 1) * WIN;
    const int cs = min(max(col0 - 1, 0), WIN - 4);

    float acc[2][4][2][2][2] = {};  // [oo][br][bc][py][px]
    const float* xb = x + (size_t)b * CIN * HW + cs;

    for (int i = 0; i < CIN; ++i) {
        const float* p = xb + (size_t)i * HW;
        half2v P[6][3];  // packed pairs starting at patch col 0,1,2
        #pragma unroll
        for (int u = 0; u < 6; ++u) {
            float4u t = *(const float4u*)(p + roff[u]);
            P[u][0] = pk_f16(t.x, t.y);
            P[u][1] = pk_f16(t.y, t.z);
            P[u][2] = pk_f16(t.z, t.w);
        }
        #pragma unroll
        for (int oo = 0; oo < 2; ++oo) {
            const uint4* wp = (const uint4*)(wlds + i * 16 + oo * 8);
            uint4 w0 = wp[0], w1 = wp[1];  // broadcast ds_read_b128 x2
            half2v W[8];
            W[0] = u2h(w0.x); W[1] = u2h(w0.y);
            W[2] = u2h(w0.z); W[3] = u2h(w0.w);
            W[4] = u2h(w1.x); W[5] = u2h(w1.y);
            W[6] = u2h(w1.z); W[7] = u2h(w1.w);
            #pragma unroll
            for (int br = 0; br < 4; ++br)
                #pragma unroll
                for (int bc = 0; bc < 2; ++bc)
                    #pragma unroll
                    for (int py = 0; py < 2; ++py)
                        #pragma unroll
                        for (int px = 0; px < 2; ++px) {
                            float s = acc[oo][br][bc][py][px];
                            s = fdot2f(P[br + py][bc + px],
                                       W[(py * 2 + px) * 2 + 0], s);
                            s = fdot2f(P[br + py + 1][bc + px],
                                       W[(py * 2 + px) * 2 + 1], s);
                            acc[oo][br][bc][py][px] = s;
                        }
        }
    }

    // Epilogue: bias + ReLU, float4 stores
    #pragma unroll
    for (int oo = 0; oo < 2; ++oo) {
        const float bse = bias_eff[b * COUT + og * 2 + oo];
        float* ob = out + (size_t)(b * COUT + og * 2 + oo) * (HOUT * WOUT);
        #pragma unroll
        for (int br = 0; br < 4; ++br)
            #pragma unroll
            for (int py = 0; py < 2; ++py) {
                int y = 2 * (row0 + br) + py;
                float4 v;
                v.x = fmaxf(acc[oo][br][0][py][0] + bse, 0.f);
                v.y = fmaxf(acc[oo][br][0][py][1] + bse, 0.f);
                v.z = fmaxf(acc[oo][br][1][py][0] + bse, 0.f);
                v.w = fmaxf(acc[oo][br][1][py][1] + bse, 0.f);
                *(float4*)&ob[(size_t)y * WOUT + 2 * col0] = v;
            }
    }
}

// ---------------------------------------------------------------------------
// Kernel D: exact fp32 recompute of border outputs the clamped main kernel
// got wrong: rows y in {0,511} (all x) and cols x in {0..3, 508..511} (all y).
// 5120 pixels per sample, all 16 output channels per thread.
// ---------------------------------------------------------------------------
__global__ __launch_bounds__(256) void fix_kernel(
    const float* __restrict__ x, const float* __restrict__ wc,
    const float* __restrict__ bias_eff, float* __restrict__ out) {
    const int b = blockIdx.y;
    const int idx = blockIdx.x * 256 + threadIdx.x;  // 0..5119
    int y, xo;
    if (idx < 1024) {
        y = (idx >> 9) * (HOUT - 1);
        xo = idx & 511;
    } else {
        int j = idx - 1024;
        const int cols[8] = {0, 1, 2, 3, WOUT - 4, WOUT - 3, WOUT - 2,
                             WOUT - 1};
        xo = cols[j >> 9];
        y = j & 511;
    }
    const int r = y >> 1, py = y & 1, c = xo >> 1, px = xo & 1;
    const float* xb = x + (size_t)b * CIN * HW;
    float acc[COUT] = {};
    for (int i = 0; i < CIN; ++i) {
        const float* p = xb + (size_t)i * HW;
        float in2[2][2];
        #pragma unroll
        for (int u = 0; u < 2; ++u)
            #pragma unroll
            for (int v = 0; v < 2; ++v) {
                int gr = r - 1 + py + u, gc = c - 1 + px + v;
                in2[u][v] = ((unsigned)gr < (unsigned)HIN &&
                             (unsigned)gc < (unsigned)WIN)
                                ? p[gr * WIN + gc]
                                : 0.f;
            }
        #pragma unroll
        for (int o = 0; o < COUT; ++o) {
            const float4 w4 = *(const float4*)(
                wc + (((size_t)(b * COUT + o) * CIN + i) << 4) +
                (py * 2 + px) * 4);
            acc[o] += w4.x * in2[0][0] + w4.y * in2[0][1] +
                      w4.z * in2[1][0] + w4.w * in2[1][1];
        }
    }
    #pragma unroll
    for (int o = 0; o < COUT; ++o) {
        float v = fmaxf(acc[o] + bias_eff[b * COUT + o], 0.f);
        out[(size_t)(b * COUT + o) * (HOUT * WOUT) + (size_t)y * WOUT + xo] = v;
    }
}

extern "C" void kernel_launch(void* const* d_in, const int* in_sizes, int n_in,
                              void* d_out, int out_size, void* d_ws, size_t ws_size,
                              hipStream_t stream) {
    const float* x      = (const float*)d_in[0];
    const float* weight = (const float*)d_in[1];
    const float* bias   = (const float*)d_in[2];
    const float* fc1_w  = (const float*)d_in[3];
    const float* fc2_w  = (const float*)d_in[4];
    const float* fc2_b  = (const float*)d_in[5];
    const float* bn_g   = (const float*)d_in[6];
    const float* bn_b   = (const float*)d_in[7];
    const float* bn_m   = (const float*)d_in[8];
    const float* bn_v   = (const float*)d_in[9];
    float* out = (float*)d_out;

    float* ws = (float*)d_ws;
    float*    pooled   = ws;                       // 256 floats
    float*    bias_eff = ws + 256;                 // 128 floats
    float*    wcbuf    = ws + 512;                 // 65536 floats (fp32 wc)
    unsigned* wch      = (unsigned*)(ws + 66048);  // 32768 dwords (f16 pairs)

    pool_kernel<<<dim3(B_ * CIN), dim3(256), 0, stream>>>(x, pooled);
    attn_weights_kernel<<<dim3(B_), dim3(256), 0, stream>>>(
        pooled, weight, bias, fc1_w, fc2_w, fc2_b, bn_g, bn_b, bn_m, bn_v,
        wcbuf, wch, bias_eff);
    conv_kernel<<<dim3(32, 8, B_), dim3(256), 0, stream>>>(
        x, wch, bias_eff, out);
    fix_kernel<<<dim3(20, B_), dim3(256), 0, stream>>>(
        x, wcbuf, bias_eff, out);
}

// Round 9
// 91.371 us; speedup vs baseline: 3.2470x; 1.7463x over previous
//
#include <hip/hip_runtime.h>
#include <hip/hip_bf16.h>

// Problem constants
#define B_  8
#define CIN 32
#define COUT 16
#define K_  4
#define HID 9
#define HIN 256
#define WIN 256
#define HW  (HIN * WIN)
#define HOUT 512
#define WOUT 512
#define TEMP 34.0f
#define EPS_ 1e-5f

#define SLAB 1168   // dwords per channel-pair slab: 34*34=1156, padded so
                    // (SLAB % 32)==16 -> lane-groups alias 2-way only (free)

typedef float f32x4 __attribute__((ext_vector_type(4)));
typedef __fp16 fp16x2 __attribute__((ext_vector_type(2)));
typedef __fp16 f16x8 __attribute__((ext_vector_type(8)));

union FragB { unsigned u[4]; f16x8 h; };

__device__ inline unsigned pk2(float a, float b) {
    union { fp16x2 f; unsigned u; } x;
    x.f = __builtin_amdgcn_cvt_pkrtz(a, b);  // a -> low half, b -> high half
    return x.u;
}
__device__ inline unsigned short f16b(float v) {
    union { __fp16 h; unsigned short u; } x;
    x.h = (__fp16)v;
    return x.u;
}

// ---------------------------------------------------------------------------
// Kernel A: pooled[b][c] = mean over HxW of x[b][c]  (== mean of upsampled)
// ---------------------------------------------------------------------------
__global__ __launch_bounds__(256) void pool_kernel(const float* __restrict__ x,
                                                   float* __restrict__ pooled) {
    int bc = blockIdx.x;  // 0..255  (b*32+c)
    const float4* p = (const float4*)(x + (size_t)bc * HW);
    float s = 0.f;
    for (int i = threadIdx.x; i < HW / 4; i += 256) {
        float4 v = p[i];
        s += v.x + v.y + v.z + v.w;
    }
    #pragma unroll
    for (int off = 32; off > 0; off >>= 1) s += __shfl_down(s, off);
    __shared__ float red[4];
    if ((threadIdx.x & 63) == 0) red[threadIdx.x >> 6] = s;
    __syncthreads();
    if (threadIdx.x == 0)
        pooled[bc] = (red[0] + red[1] + red[2] + red[3]) * (1.f / HW);
}

// ---------------------------------------------------------------------------
// Kernel B: attention -> aggregated, BN-folded, parity-combined 2x2 weights,
// packed f16 in the MFMA A-fragment layout:
// ushort index = (((b*16 + par*4 + ks)*64 + (g*16+o))*4 + tap)*2 + (i&1)
// with ks = i>>3, g = (i>>1)&3  (channel-pair halves, tap-per-dword).
// A and B fragments share the same (lane-group, dword, half) -> k map, so
// any hardware k-permutation cancels as long as both sides use this layout.
// ---------------------------------------------------------------------------
__global__ __launch_bounds__(256) void attn_weights_kernel(
    const float* __restrict__ pooled, const float* __restrict__ weight,
    const float* __restrict__ bias, const float* __restrict__ fc1_w,
    const float* __restrict__ fc2_w, const float* __restrict__ fc2_b,
    const float* __restrict__ gamma, const float* __restrict__ beta,
    const float* __restrict__ mean, const float* __restrict__ var,
    unsigned short* __restrict__ wpk16, float* __restrict__ bias_eff) {
    int b = blockIdx.x;
    __shared__ float attn[K_];
    if (threadIdx.x == 0) {
        const float* pb = pooled + b * CIN;
        float h[HID];
        for (int j = 0; j < HID; ++j) {
            float s = 0.f;
            for (int c = 0; c < CIN; ++c) s += pb[c] * fc1_w[j * CIN + c];
            h[j] = fmaxf(s, 0.f);
        }
        float lg[K_];
        float mx = -1e30f;
        for (int k = 0; k < K_; ++k) {
            float s = fc2_b[k];
            for (int j = 0; j < HID; ++j) s += h[j] * fc2_w[k * HID + j];
            lg[k] = s * (1.f / TEMP);
            mx = fmaxf(mx, lg[k]);
        }
        float den = 0.f;
        for (int k = 0; k < K_; ++k) { lg[k] = expf(lg[k] - mx); den += lg[k]; }
        for (int k = 0; k < K_; ++k) attn[k] = lg[k] / den;
    }
    __syncthreads();
    float a0 = attn[0], a1 = attn[1], a2 = attn[2], a3v = attn[3];

    for (int p = threadIdx.x; p < COUT * CIN; p += 256) {
        int o = p >> 5, i = p & 31;
        float scale = gamma[o] / sqrtf(var[o] + EPS_);
        const float* w0 = weight + ((size_t)(0 * COUT + o) * CIN + i) * 9;
        const int kstr = COUT * CIN * 9;  // 4608
        float a3w[9];
        #pragma unroll
        for (int t = 0; t < 9; ++t)
            a3w[t] = scale * (a0 * w0[t] + a1 * w0[kstr + t] +
                              a2 * w0[2 * kstr + t] + a3v * w0[3 * kstr + t]);
        float tmp[2][2][3];
        #pragma unroll
        for (int kx = 0; kx < 3; ++kx) {
            tmp[0][0][kx] = a3w[0 * 3 + kx];
            tmp[0][1][kx] = a3w[1 * 3 + kx] + a3w[2 * 3 + kx];
            tmp[1][0][kx] = a3w[0 * 3 + kx] + a3w[1 * 3 + kx];
            tmp[1][1][kx] = a3w[2 * 3 + kx];
        }
        float w16[16];  // [par(py,px)][tap(u,v)] = [par*4 + u*2+v]
        #pragma unroll
        for (int py = 0; py < 2; ++py)
            #pragma unroll
            for (int px = 0; px < 2; ++px)
                #pragma unroll
                for (int u = 0; u < 2; ++u)
                    #pragma unroll
                    for (int v = 0; v < 2; ++v) {
                        const float* t = tmp[py][u];
                        float val = (px == 0) ? (v == 0 ? t[0] : t[1] + t[2])
                                              : (v == 0 ? t[0] + t[1] : t[2]);
                        w16[(py * 2 + px) * 4 + u * 2 + v] = val;
                    }
        const int ks = i >> 3, g = (i >> 1) & 3, hf = i & 1;
        const int l = g * 16 + o;
        #pragma unroll
        for (int par = 0; par < 4; ++par)
            #pragma unroll
            for (int d = 0; d < 4; ++d)
                wpk16[(((size_t)(b * 16 + par * 4 + ks) * 64 + l) * 4 + d) * 2 +
                      hf] = f16b(w16[par * 4 + d]);
    }
    if (threadIdx.x < COUT) {
        int o = threadIdx.x;
        float scale = gamma[o] / sqrtf(var[o] + EPS_);
        float shift = beta[o] - mean[o] * scale;
        float s = a0 * bias[0 * COUT + o] + a1 * bias[1 * COUT + o] +
                  a2 * bias[2 * COUT + o] + a3v * bias[3 * COUT + o];
        bias_eff[b * COUT + o] = s * scale + shift;
    }
}

// ---------------------------------------------------------------------------
// Kernel C: fused upsample+conv+BN+ReLU via MFMA (16x16x32 f16).
// Block: (b, 32x32 input-base tile) -> 64x64 outputs x 16 o.
// Stage: whole 34x34 halo x 32 channels as f16 channel-pair dwords in LDS
// (zero-padded -> borders exact, no fix kernel). Compute: per 16-base group,
// per K-step, 9 ds_read_b32 (3x3 neighborhood) feed all 4 parity MFMAs.
// ---------------------------------------------------------------------------
__global__ __launch_bounds__(256, 2) void conv_kernel(
    const float* __restrict__ x, const unsigned* __restrict__ wpk,
    const float* __restrict__ bias_eff, float* __restrict__ out) {
    const int tile = blockIdx.x;   // 0..63
    const int b = blockIdx.y;      // 0..7
    const int r0 = (tile >> 3) * 32, c0 = (tile & 7) * 32;
    const int tid = threadIdx.x;

    __shared__ unsigned lds32[16 * SLAB];  // 74,752 B

    const float* xb = x + (size_t)b * CIN * HW;

    // ---- stage: channel-pair f16 packing, zero-padded halo ----
    for (int i2 = 0; i2 < 16; ++i2) {
        const float* p0 = xb + (size_t)(2 * i2) * HW;
        for (int e = tid; e < 34 * 34; e += 256) {
            int pr = e / 34, pc = e - pr * 34;
            int gr = r0 - 1 + pr, gc = c0 - 1 + pc;
            bool ok = ((unsigned)gr < (unsigned)HIN) &
                      ((unsigned)gc < (unsigned)WIN);
            int off = ok ? (gr * WIN + gc) : 0;
            float v0 = p0[off];
            float v1 = p0[off + HW];
            if (!ok) { v0 = 0.f; v1 = 0.f; }
            lds32[i2 * SLAB + e] = pk2(v0, v1);
        }
    }
    __syncthreads();

    const int w = tid >> 6, lane = tid & 63;
    const int g = lane >> 4, n = lane & 15;

    // A fragments [par][ks]: 8 f16 each, coalesced 16B loads
    f16x8 areg[4][4];
    {
        const f16x8* wp = (const f16x8*)wpk + (size_t)b * 1024 + lane;
        #pragma unroll
        for (int par = 0; par < 4; ++par)
            #pragma unroll
            for (int ks = 0; ks < 4; ++ks)
                areg[par][ks] = wp[(par * 4 + ks) * 64];
    }
    float bias4[4];
    #pragma unroll
    for (int q = 0; q < 4; ++q) bias4[q] = bias_eff[b * COUT + g * 4 + q];

    // each wave: 16 groups = 8 base rows x 2 column halves
    for (int gi = 0; gi < 16; ++gi) {
        const int r = (w << 3) + (gi >> 1);   // local base row 0..31
        const int h = gi & 1;                 // column half
        const int ab = g * SLAB + r * 34 + (h << 4) + n;

        f32x4 acc[4];
        #pragma unroll
        for (int par = 0; par < 4; ++par)
            acc[par] = (f32x4){0.f, 0.f, 0.f, 0.f};

        #pragma unroll
        for (int ks = 0; ks < 4; ++ks) {
            unsigned nb[3][3];
            #pragma unroll
            for (int du = 0; du < 3; ++du)
                #pragma unroll
                for (int dv = 0; dv < 3; ++dv)
                    nb[du][dv] = lds32[ab + ks * (4 * SLAB) + du * 34 + dv];
            #pragma unroll
            for (int par = 0; par < 4; ++par) {
                const int py = par >> 1, px = par & 1;
                FragB bf;
                bf.u[0] = nb[py][px];
                bf.u[1] = nb[py][px + 1];
                bf.u[2] = nb[py + 1][px];
                bf.u[3] = nb[py + 1][px + 1];
                acc[par] = __builtin_amdgcn_mfma_f32_16x16x32_f16(
                    areg[par][ks], bf.h, acc[par], 0, 0, 0);
            }
        }

        // epilogue: bias + ReLU, direct f32 stores
        #pragma unroll
        for (int par = 0; par < 4; ++par) {
            const int py = par >> 1, px = par & 1;
            const int y = 2 * (r0 + r) + py;
            const int xg = 2 * (c0 + (h << 4) + n) + px;
            #pragma unroll
            for (int q = 0; q < 4; ++q) {
                float vv = fmaxf(acc[par][q] + bias4[q], 0.f);
                out[((size_t)(b * COUT + g * 4 + q) * HOUT + y) * WOUT + xg] =
                    vv;
            }
        }
    }
}

extern "C" void kernel_launch(void* const* d_in, const int* in_sizes, int n_in,
                              void* d_out, int out_size, void* d_ws, size_t ws_size,
                              hipStream_t stream) {
    const float* x      = (const float*)d_in[0];
    const float* weight = (const float*)d_in[1];
    const float* bias   = (const float*)d_in[2];
    const float* fc1_w  = (const float*)d_in[3];
    const float* fc2_w  = (const float*)d_in[4];
    const float* fc2_b  = (const float*)d_in[5];
    const float* bn_g   = (const float*)d_in[6];
    const float* bn_b   = (const float*)d_in[7];
    const float* bn_m   = (const float*)d_in[8];
    const float* bn_v   = (const float*)d_in[9];
    float* out = (float*)d_out;

    float* ws = (float*)d_ws;
    float*    pooled   = ws;                      // 256 floats
    float*    bias_eff = ws + 256;                // 128 floats
    unsigned* wpk      = (unsigned*)(ws + 512);   // 32768 dwords (f16 pairs)

    pool_kernel<<<dim3(B_ * CIN), dim3(256), 0, stream>>>(x, pooled);
    attn_weights_kernel<<<dim3(B_), dim3(256), 0, stream>>>(
        pooled, weight, bias, fc1_w, fc2_w, fc2_b, bn_g, bn_b, bn_m, bn_v,
        (unsigned short*)wpk, bias_eff);
    conv_kernel<<<dim3(64, B_), dim3(256), 0, stream>>>(
        x, wpk, bias_eff, out);
}